// Round 5
// baseline (34.701 us; speedup 1.0000x reference)
//
#include <hip/hip_runtime.h>

#define H_IMG   500
#define W_IMG   512
#define KPP     10
#define N_PTS   8192
#define TILE    16
#define TX_TILES 32              // 512/16
#define TY_TILES 32              // ceil(500/16); rows >= 500 masked at store
#define N_TILES (TX_TILES * TY_TILES)
#define CAP     256              // max pts per tile (center density ~30; no observed overflow)
#define IMG_ELEMS (H_IMG * W_IMG * 3)   // 768000

// ---------------------------------------------------------------------------
// Round-5 structure (attacking the round-invariant ~30us):
//   memset(cnts, 4KB)
//   Kernel A: 8192 threads project once (exact f32 op order), bbox-cull,
//             append (pos,idx) + (feat triple) entries to per-tile lists.
//   Kernel B: per 16x16 tile: load ~n<=CAP entries -> LDS, per-pixel top-KPP
//             in named registers (slot-tracked), epilogue reads feats from
//             LDS (no divergent global gathers), stages img+zbuf in LDS and
//             stores fully coalesced.
// ---------------------------------------------------------------------------

// sorted bubble-insert stage: ascending (z, idx); branchless; tracks LDS slot
#define INSERT(ZZ, DD, II, SS)                                         \
    {                                                                  \
        bool lt = (cz < ZZ) || ((cz == ZZ) && (ci < II));              \
        float tz = ZZ, td = DD; int ti = II, ts = SS;                  \
        ZZ = lt ? cz : ZZ;  DD = lt ? cd : DD;                         \
        II = lt ? ci : II;  SS = lt ? cs : SS;                         \
        cz = lt ? tz : cz;  cd = lt ? td : cd;                         \
        ci = lt ? ti : ci;  cs = lt ? ts : cs;                         \
    }

// epilogue stage k: weight, composite (feats from LDS), stage zbuf in LDS
#define EMIT(K, ZZ, DD, SS)                                            \
    {                                                                  \
        bool ok = ZZ < __builtin_inff();                               \
        float wt = ok ? (1.0f - DD / R2) : 0.0f;                       \
        float a = wt * T;                                              \
        if (ok) {                                                      \
            float4 f = sf[SS];                                         \
            c0 += a * f.x;                                             \
            c1 += a * f.y;                                             \
            c2 += a * f.z;                                             \
        }                                                              \
        T = T * (1.0f - wt);                                           \
        szb[ty][tx * KPP + K] = ok ? ZZ : -1.0f;                       \
    }

// ---- Kernel A: project + bin all points once ----
__global__ __launch_bounds__(256) void pcd_bin_kernel(
        const float* __restrict__ pts,
        const float* __restrict__ feats,
        int* __restrict__ cnts,
        float4* __restrict__ posArr,
        float4* __restrict__ featArr) {
#pragma clang fp contract(off)
    int i = blockIdx.x * 256 + threadIdx.x;   // grid exactly N_PTS threads

    float x = pts[i * 3 + 0];
    float y = pts[i * 3 + 1];
    float z = pts[i * 3 + 2];

    // exact reference op order: u = -FX*x/z + PX ; xn = -(2u - W)/S_MIN
    float u  = -575.0f * x / z + 256.0f;
    float v  = -575.0f * y / z + 250.0f;
    float xn = -(2.0f * u - 512.0f) / 500.0f;
    float yn = -(2.0f * v - 500.0f) / 500.0f;

    if (!(z > 0.0f)) return;   // reference: valid requires z > 0

    const float R = 0.005f;
    // pixel w satisfies |xs[w]-xn|<R with xs[w] = (W-1-2w)/S_MIN ; +/-1 px slack
    float wlo_f = (511.0f - 500.0f * (xn + R)) * 0.5f - 1.0f;
    float whi_f = (511.0f - 500.0f * (xn - R)) * 0.5f + 1.0f;
    float hlo_f = (499.0f - 500.0f * (yn + R)) * 0.5f - 1.0f;
    float hhi_f = (499.0f - 500.0f * (yn - R)) * 0.5f + 1.0f;

    wlo_f = fmaxf(fminf(wlo_f, 1.0e6f), -1.0e6f);
    whi_f = fmaxf(fminf(whi_f, 1.0e6f), -1.0e6f);
    hlo_f = fmaxf(fminf(hlo_f, 1.0e6f), -1.0e6f);
    hhi_f = fmaxf(fminf(hhi_f, 1.0e6f), -1.0e6f);

    int wlo = max(0, (int)floorf(wlo_f));
    int whi = min(W_IMG - 1, (int)ceilf(whi_f));
    int hlo = max(0, (int)floorf(hlo_f));
    int hhi = min(H_IMG - 1, (int)ceilf(hhi_f));
    if (wlo > whi || hlo > hhi) return;

    float4 pe = make_float4(xn, yn, z, __int_as_float(i));
    float4 fe = make_float4(feats[i * 3 + 0], feats[i * 3 + 1], feats[i * 3 + 2], 0.0f);

    int tx0 = wlo >> 4, tx1 = whi >> 4;
    int ty0 = hlo >> 4, ty1 = hhi >> 4;
    for (int ty = ty0; ty <= ty1; ++ty) {
        for (int tx = tx0; tx <= tx1; ++tx) {
            int t = ty * TX_TILES + tx;
            int pos = atomicAdd(&cnts[t], 1);
            if (pos < CAP) {
                posArr[t * CAP + pos] = pe;
                featArr[t * CAP + pos] = fe;
            }
        }
    }
}

// ---- Kernel B: per-tile render ----
__global__ __launch_bounds__(256) void pcd_render_kernel(
        const int* __restrict__ cnts,
        const float4* __restrict__ posArr,
        const float4* __restrict__ featArr,
        float* __restrict__ out) {
#pragma clang fp contract(off)
    __shared__ float4 sp[CAP];
    __shared__ float4 sf[CAP];
    __shared__ float szb[TILE][TILE * KPP + 1];   // +1 pad: break ty bank collision
    __shared__ float simg[TILE][TILE * 3 + 1];

    const int tile = blockIdx.x;
    const int w0 = (tile & (TX_TILES - 1)) * TILE;
    const int h0 = (tile >> 5) * TILE;

    int n = cnts[tile];
    n = n < CAP ? n : CAP;

    for (int j = threadIdx.x; j < n; j += 256) {
        sp[j] = posArr[tile * CAP + j];
        sf[j] = featArr[tile * CAP + j];
    }
    __syncthreads();

    const int tx = threadIdx.x & 15;
    const int ty = threadIdx.x >> 4;
    const int w = w0 + tx;
    const int h = h0 + ty;

    const float xs = -(2.0f * ((float)w + 0.5f) - 512.0f) / 500.0f;
    const float ys = -(2.0f * ((float)h + 0.5f) - 500.0f) / 500.0f;
    const float R2 = 0.005f * 0.005f;
    const float INF = __builtin_inff();

    float kz0 = INF, kz1 = INF, kz2 = INF, kz3 = INF, kz4 = INF;
    float kz5 = INF, kz6 = INF, kz7 = INF, kz8 = INF, kz9 = INF;
    float kd0 = 0, kd1 = 0, kd2 = 0, kd3 = 0, kd4 = 0;
    float kd5 = 0, kd6 = 0, kd7 = 0, kd8 = 0, kd9 = 0;
    int ki0 = 0x7fffffff, ki1 = 0x7fffffff, ki2 = 0x7fffffff, ki3 = 0x7fffffff, ki4 = 0x7fffffff;
    int ki5 = 0x7fffffff, ki6 = 0x7fffffff, ki7 = 0x7fffffff, ki8 = 0x7fffffff, ki9 = 0x7fffffff;
    int ks0 = 0, ks1 = 0, ks2 = 0, ks3 = 0, ks4 = 0;
    int ks5 = 0, ks6 = 0, ks7 = 0, ks8 = 0, ks9 = 0;

    for (int j = 0; j < n; ++j) {
        float4 p = sp[j];                 // uniform addr across wave -> LDS broadcast
        float dx = xs - p.x;
        float dy = ys - p.y;
        float dx2 = dx * dx;              // contract(off): separate roundings like numpy
        float dy2 = dy * dy;
        float d2 = dx2 + dy2;
        if (d2 < R2) {
            float cz = p.z, cd = d2;
            int ci = __float_as_int(p.w);
            int cs = j;
            INSERT(kz0, kd0, ki0, ks0);
            INSERT(kz1, kd1, ki1, ks1);
            INSERT(kz2, kd2, ki2, ks2);
            INSERT(kz3, kd3, ki3, ks3);
            INSERT(kz4, kd4, ki4, ks4);
            INSERT(kz5, kd5, ki5, ks5);
            INSERT(kz6, kd6, ki6, ks6);
            INSERT(kz7, kd7, ki7, ks7);
            INSERT(kz8, kd8, ki8, ks8);
            INSERT(kz9, kd9, ki9, ks9);
        }
    }

    // epilogue into LDS staging (all threads participate; masked at store)
    {
        float T = 1.0f;
        float c0 = 0.0f, c1 = 0.0f, c2 = 0.0f;
        EMIT(0, kz0, kd0, ks0);
        EMIT(1, kz1, kd1, ks1);
        EMIT(2, kz2, kd2, ks2);
        EMIT(3, kz3, kd3, ks3);
        EMIT(4, kz4, kd4, ks4);
        EMIT(5, kz5, kd5, ks5);
        EMIT(6, kz6, kd6, ks6);
        EMIT(7, kz7, kd7, ks7);
        EMIT(8, kz8, kd8, ks8);
        EMIT(9, kz9, kd9, ks9);
        simg[ty][tx * 3 + 0] = c0;
        simg[ty][tx * 3 + 1] = c1;
        simg[ty][tx * 3 + 2] = c2;
    }
    __syncthreads();

    // coalesced cooperative stores
    // zbuf: 16 rows x 160 contiguous floats each
    for (int e = threadIdx.x; e < TILE * TILE * KPP; e += 256) {
        int r = e / (TILE * KPP);
        int c = e - r * (TILE * KPP);
        int hh = h0 + r;
        if (hh < H_IMG)
            out[IMG_ELEMS + (hh * W_IMG + w0) * KPP + c] = szb[r][c];
    }
    // img: 16 rows x 48 contiguous floats each
    for (int e = threadIdx.x; e < TILE * TILE * 3; e += 256) {
        int r = e / (TILE * 3);
        int c = e - r * (TILE * 3);
        int hh = h0 + r;
        if (hh < H_IMG)
            out[(hh * W_IMG + w0) * 3 + c] = simg[r][c];
    }
}

// ---------------------------------------------------------------------------
extern "C" void kernel_launch(void* const* d_in, const int* in_sizes, int n_in,
                              void* d_out, int out_size, void* d_ws, size_t ws_size,
                              hipStream_t stream) {
    const float* points = (const float*)d_in[0];   // (8192, 3) f32
    const float* feats  = (const float*)d_in[1];   // (8192, 3) f32
    float* out = (float*)d_out;                    // 768000 img + 2560000 zbuf f32

    // workspace layout (16B-aligned slabs)
    int* cnts = (int*)d_ws;                                         // 1024 * 4 B
    float4* posArr  = (float4*)((char*)d_ws + 4096);                // 1024*256*16 B = 4 MB
    float4* featArr = (float4*)((char*)d_ws + 4096 + N_TILES * CAP * 16);

    hipMemsetAsync(cnts, 0, N_TILES * sizeof(int), stream);
    pcd_bin_kernel<<<N_PTS / 256, 256, 0, stream>>>(points, feats, cnts, posArr, featArr);
    pcd_render_kernel<<<N_TILES, 256, 0, stream>>>(cnts, posArr, featArr, out);
}